// Round 1
// baseline (792.609 us; speedup 1.0000x reference)
//
#include <hip/hip_runtime.h>
#include <hip/hip_bf16.h>
#include <math.h>

#define EPS_INV 20.0f
#define B_ROWS 16384
#define K_COLS 4096

// ---- ordered-uint encoding for float atomicMax (works for negatives) ----
__device__ __forceinline__ unsigned enc_f(float f) {
  unsigned u = __float_as_uint(f);
  return (u & 0x80000000u) ? ~u : (u | 0x80000000u);
}
__device__ __forceinline__ float dec_f(unsigned u) {
  u = (u & 0x80000000u) ? (u ^ 0x80000000u) : ~u;
  return __uint_as_float(u);
}

// ---- pass 0: global max of logits ----
__global__ void k_max(const float4* __restrict__ x, unsigned* __restrict__ gmax, int n4) {
  int tid = blockIdx.x * blockDim.x + threadIdx.x;
  int stride = gridDim.x * blockDim.x;
  float m = -3.4e38f;
  for (int i = tid; i < n4; i += stride) {
    float4 v = x[i];
    m = fmaxf(m, fmaxf(fmaxf(v.x, v.y), fmaxf(v.z, v.w)));
  }
  #pragma unroll
  for (int off = 32; off > 0; off >>= 1)
    m = fmaxf(m, __shfl_xor(m, off, 64));
  if ((threadIdx.x & 63) == 0) atomicMax(gmax, enc_f(m));
}

// ---- column sums: T[k] = sum_b w(b) * exp((l[b,k]-m)*20), w = beta or 1 ----
// grid: (4 col-tiles of 1024, 256 row-tiles of 64). Thread owns 4 consecutive cols.
__global__ void k_colsum(const float* __restrict__ logits,
                         const unsigned* __restrict__ gmaxp,
                         const float* __restrict__ beta,   // may be null (weight 1)
                         float* __restrict__ T, int rows_per_block) {
  float m = dec_f(*gmaxp);
  int c0 = blockIdx.x * 1024 + threadIdx.x * 4;
  int r0 = blockIdx.y * rows_per_block;
  float4 acc = make_float4(0.f, 0.f, 0.f, 0.f);
  for (int r = r0; r < r0 + rows_per_block; ++r) {
    float w = beta ? beta[r] : 1.0f;   // wave-uniform branch
    float4 v = *(const float4*)(logits + (size_t)r * K_COLS + c0);
    acc.x += w * __expf((v.x - m) * EPS_INV);
    acc.y += w * __expf((v.y - m) * EPS_INV);
    acc.z += w * __expf((v.z - m) * EPS_INV);
    acc.w += w * __expf((v.w - m) * EPS_INV);
  }
  atomicAdd(T + c0 + 0, acc.x);
  atomicAdd(T + c0 + 1, acc.y);
  atomicAdd(T + c0 + 2, acc.z);
  atomicAdd(T + c0 + 3, acc.w);
}

// ---- alpha1: S = sum T0; alpha[k] = (S/K) / T0[k] ----
__global__ void k_alpha1(const float* __restrict__ T0, float* __restrict__ alpha) {
  __shared__ float sred[4];
  int tid = threadIdx.x;
  float s = 0.f;
  for (int i = tid; i < K_COLS; i += 256) s += T0[i];
  #pragma unroll
  for (int off = 32; off > 0; off >>= 1) s += __shfl_xor(s, off, 64);
  if ((tid & 63) == 0) sred[tid >> 6] = s;
  __syncthreads();
  float S = sred[0] + sred[1] + sred[2] + sred[3];
  float c = S * (1.0f / (float)K_COLS);
  for (int i = tid; i < K_COLS; i += 256) alpha[i] = c / T0[i];
}

// ---- alpha from T: alpha[k] = (1/K) / T[k] ----
__global__ void k_alpha_from_T(const float* __restrict__ T, float* __restrict__ alpha) {
  int i = blockIdx.x * blockDim.x + threadIdx.x;
  if (i < K_COLS) alpha[i] = (1.0f / (float)K_COLS) / T[i];
}

// ---- row sums: beta[b] = (1/B) / sum_k alpha[k]*exp((l[b,k]-m)*20) ----
// one wave per row, 4 waves/block
__global__ void k_rowsum_beta(const float* __restrict__ logits,
                              const unsigned* __restrict__ gmaxp,
                              const float* __restrict__ alpha,
                              float* __restrict__ beta) {
  float m = dec_f(*gmaxp);
  int lane = threadIdx.x & 63;
  int r = blockIdx.x * 4 + (threadIdx.x >> 6);
  const float4* row = (const float4*)(logits + (size_t)r * K_COLS);
  const float4* a4 = (const float4*)alpha;
  float acc = 0.f;
  #pragma unroll
  for (int j = 0; j < 16; ++j) {
    int i = lane + j * 64;
    float4 v = row[i];
    float4 a = a4[i];
    acc += a.x * __expf((v.x - m) * EPS_INV)
         + a.y * __expf((v.y - m) * EPS_INV)
         + a.z * __expf((v.z - m) * EPS_INV)
         + a.w * __expf((v.w - m) * EPS_INV);
  }
  #pragma unroll
  for (int off = 32; off > 0; off >>= 1) acc += __shfl_xor(acc, off, 64);
  if (lane == 0) beta[r] = (1.0f / (float)B_ROWS) / acc;
}

// ---- finalize: out[b,k] = alpha[k]*E[b,k] / sum_k alpha[k]*E[b,k] ----
__global__ void k_finalize(const float* __restrict__ logits,
                           const unsigned* __restrict__ gmaxp,
                           const float* __restrict__ alpha,
                           float4* __restrict__ out) {
  float m = dec_f(*gmaxp);
  int lane = threadIdx.x & 63;
  int r = blockIdx.x * 4 + (threadIdx.x >> 6);
  const float4* row = (const float4*)(logits + (size_t)r * K_COLS);
  const float4* a4 = (const float4*)alpha;
  float4 prod[16];
  float acc = 0.f;
  #pragma unroll
  for (int j = 0; j < 16; ++j) {
    int i = lane + j * 64;
    float4 v = row[i];
    float4 a = a4[i];
    float4 p;
    p.x = a.x * __expf((v.x - m) * EPS_INV);
    p.y = a.y * __expf((v.y - m) * EPS_INV);
    p.z = a.z * __expf((v.z - m) * EPS_INV);
    p.w = a.w * __expf((v.w - m) * EPS_INV);
    prod[j] = p;
    acc += p.x + p.y + p.z + p.w;
  }
  #pragma unroll
  for (int off = 32; off > 0; off >>= 1) acc += __shfl_xor(acc, off, 64);
  float inv = 1.0f / acc;  // butterfly: all lanes hold the full row sum
  float4* orow = out + (size_t)r * (K_COLS / 4);
  #pragma unroll
  for (int j = 0; j < 16; ++j) {
    int i = lane + j * 64;
    float4 p = prod[j];
    p.x *= inv; p.y *= inv; p.z *= inv; p.w *= inv;
    orow[i] = p;
  }
}

extern "C" void kernel_launch(void* const* d_in, const int* in_sizes, int n_in,
                              void* d_out, int out_size, void* d_ws, size_t ws_size,
                              hipStream_t stream) {
  const float* logits = (const float*)d_in[0];
  char* ws = (char*)d_ws;

  // ws layout (all small): [0] gmax bits; [1024] T0[4096]; T1; T2; alpha[4096]; beta[16384]
  unsigned* gmax = (unsigned*)ws;
  float* T0    = (float*)(ws + 1024);
  float* T1    = T0 + K_COLS;
  float* T2    = T1 + K_COLS;
  float* alpha = T2 + K_COLS;
  float* beta  = alpha + K_COLS;

  // zero gmax + T0..T2 (ws is poisoned 0xAA before every launch)
  hipMemsetAsync(d_ws, 0, 1024 + 3 * K_COLS * sizeof(float), stream);

  const int n4 = (B_ROWS * K_COLS) / 4;
  k_max<<<2048, 256, 0, stream>>>((const float4*)logits, gmax, n4);

  dim3 cs_grid(4, 256);  // 4 col-tiles x 256 row-tiles (64 rows each)
  k_colsum<<<cs_grid, 256, 0, stream>>>(logits, gmax, nullptr, T0, 64);
  k_alpha1<<<1, 256, 0, stream>>>(T0, alpha);

  k_rowsum_beta<<<B_ROWS / 4, 256, 0, stream>>>(logits, gmax, alpha, beta);
  k_colsum<<<cs_grid, 256, 0, stream>>>(logits, gmax, beta, T1, 64);
  k_alpha_from_T<<<K_COLS / 256, 256, 0, stream>>>(T1, alpha);

  k_rowsum_beta<<<B_ROWS / 4, 256, 0, stream>>>(logits, gmax, alpha, beta);
  k_colsum<<<cs_grid, 256, 0, stream>>>(logits, gmax, beta, T2, 64);
  k_alpha_from_T<<<K_COLS / 256, 256, 0, stream>>>(T2, alpha);

  k_finalize<<<B_ROWS / 4, 256, 0, stream>>>(logits, gmax, alpha, (float4*)d_out);
}